// Round 6
// baseline (191.798 us; speedup 1.0000x reference)
//
#include <hip/hip_runtime.h>

// ---------------------------------------------------------------------------
// out[b,i] = (x@L^T)[b,i] + quad_mean[b] + cubic_mean[b] + (i==0)*cT[b] + (i==1)*cH[b]
// quad_mean[b] = sum_h relu(x@qW1 + qb1)[b,h] * colmean(qW2)[h] + mean(qb2)
//
// Round 6: GEMM inner loop switched 16x16x32 -> 32x32x16 MFMA (2x2 frags per
// wave, same 64x64 wave tile). Same LDS traffic, HALF the MFMA instruction
// count, ~15% higher MFMA-pipe rate (m119). Staging + swizzle identical to
// round 5 (BK=64, chunk (row,kc) at slot kc^(row&7), conflict-free).
// Structure: prep_conv -> nl_gemm -> lin_gemm (3 launches).
// ---------------------------------------------------------------------------

#define OMEGA_F 0.5235987755982988f

typedef __attribute__((ext_vector_type(8))) short short8;
typedef __attribute__((ext_vector_type(16))) float f32x16;

__device__ __forceinline__ unsigned short f2bf(float f) {
  union { float f; unsigned int u; } a;
  a.f = f;
  unsigned int u = a.u;
  return (unsigned short)((u + 0x7fffu + ((u >> 16) & 1u)) >> 16);
}

// async global -> LDS, 16 B per lane; LDS dst wave-uniform, lane i -> base+i*16
__device__ __forceinline__ void gload16(const void* g, void* l) {
  __builtin_amdgcn_global_load_lds(
      (const __attribute__((address_space(1))) unsigned int*)g,
      (__attribute__((address_space(3))) unsigned int*)l, 16, 0, 0);
}

// ---- k1: all prep work in one launch ---------------------------------------
__global__ void prep_conv(const float* __restrict__ fc, const float* __restrict__ qW1,
                          const float* __restrict__ cW1, const float* __restrict__ t,
                          const float* __restrict__ qW2, const float* __restrict__ cW2,
                          const float* __restrict__ qb2, const float* __restrict__ cb2,
                          const float4* __restrict__ x4, const float* __restrict__ x,
                          const float* __restrict__ tW1, const float* __restrict__ tb1,
                          const float* __restrict__ tW2, const float* __restrict__ tb2,
                          const float* __restrict__ hW1, const float* __restrict__ hb1,
                          const float* __restrict__ hW2, const float* __restrict__ hb2,
                          unsigned short* __restrict__ WT, uint2* __restrict__ xb,
                          float* __restrict__ qw2m, float* __restrict__ cw2m,
                          float* __restrict__ b2m, float* __restrict__ cT,
                          float* __restrict__ cH, float* __restrict__ rowadd) {
  int b = blockIdx.x, tdx = threadIdx.x;
  if (b < 3072) {
    // WcatT (1536 x 512 bf16, n-major): [ L | quad_W1^T | cubic_W1^T ]
    int idx = b * 256 + tdx;
    int n = idx >> 9;
    int k = idx & 511;
    float v;
    if (n < 512) {
      float th = OMEGA_F * t[0];
      float s1, c1, s2, c2;
      sincosf(th, &s1, &c1);
      sincosf(2.0f * th, &s2, &c2);
      const float* p = fc + ((size_t)n * 512 + k) * 5;
      v = p[0] + p[1] * c1 + p[2] * s1 + p[3] * c2 + p[4] * s2;
    } else if (n < 1024) {
      v = qW1[(size_t)k * 512 + (n - 512)];
    } else {
      v = cW1[(size_t)k * 512 + (n - 1024)];
    }
    WT[idx] = f2bf(v);
  } else if (b < 3076) {
    int bb = b - 3072;
    const float* W = (bb < 2) ? qW2 : cW2;
    float* o = (bb < 2) ? qw2m : cw2m;
    int h = (bb & 1) * 256 + tdx;
    const float4* row = (const float4*)(W + (size_t)h * 512);
    float s = 0.f;
    for (int i = 0; i < 128; ++i) { float4 v = row[i]; s += (v.x + v.y) + (v.z + v.w); }
    o[h] = s * (1.0f / 512.0f);
  } else if (b == 3076) {
    __shared__ float sm[256];
    sm[tdx] = qb2[tdx] + qb2[tdx + 256];
    __syncthreads();
    for (int w = 128; w > 0; w >>= 1) { if (tdx < w) sm[tdx] += sm[tdx + w]; __syncthreads(); }
    if (tdx == 0) b2m[0] = sm[0] * (1.0f / 512.0f);
    __syncthreads();
    sm[tdx] = cb2[tdx] + cb2[tdx + 256];
    __syncthreads();
    for (int w = 128; w > 0; w >>= 1) { if (tdx < w) sm[tdx] += sm[tdx + w]; __syncthreads(); }
    if (tdx == 0) b2m[1] = sm[0] * (1.0f / 512.0f);
  } else if (b < 3077 + 8192) {
    // x -> bf16
    int i = (b - 3077) * 256 + tdx;
    float4 v = x4[i];
    uint2 r;
    r.x = (unsigned)f2bf(v.x) | ((unsigned)f2bf(v.y) << 16);
    r.y = (unsigned)f2bf(v.z) | ((unsigned)f2bf(v.w) << 16);
    xb[i] = r;
  } else {
    // enso tiny MLPs + rowadd zeroing
    int row = (b - 11269) * 256 + tdx;
    rowadd[row] = 0.f;
    float T = x[(size_t)row * 512];
    float H = x[(size_t)row * 512 + 1];
    float fT[5] = {T, H, T * T, T * H, T * T * T};
    float fH[5] = {T, H, T * T, T * H, T * H * H};
    float sT = tb2[0], sH = hb2[0];
#pragma unroll 4
    for (int e = 0; e < 32; ++e) {
      float a1 = tb1[e], a2 = hb1[e];
#pragma unroll
      for (int f = 0; f < 5; ++f) {
        a1 += fT[f] * tW1[f * 32 + e];
        a2 += fH[f] * hW1[f * 32 + e];
      }
      sT += fmaxf(a1, 0.f) * tW2[e];
      sH += fmaxf(a2, 0.f) * hW2[e];
    }
    cT[row] = sT;
    cH[row] = sH;
  }
}

// ---------------------------------------------------------------------------
// GEMM main loop: 128x128 tile, BK=64, global_load_lds(16B) staging,
// 32x32x16 bf16 MFMA (each wave: 64x64 = 2x2 frags).
// LDS: row-major 128 x 64 elems; 16B chunk (row, c) stored at slot c^(row&7).
//  - staging (same as r5): issue i, wave w rows (i*4+w)*8..+7; lane l fetches
//    global chunk (l&7)^(l>>3) of row +(l>>3) -> lands at slot l&7 ✓.
//  - frag read: A[m=lane&31][k=(lane>>5)*8+j], chunk c = kc*2+(lane>>5),
//    slot = c ^ (lane&7)  (row&7 == lane&7: all row offsets are mult of 8).
//    8-lane groups cover all 8 bank-quads -> conflict-free.
//  - C/D: col = lane&31, row = (reg&3) + 8*(reg>>2) + 4*(lane>>5) (m74/m101).
// ---------------------------------------------------------------------------
#define GEMM_MAINLOOP(A_, Bt_)                                                    \
  __shared__ unsigned short As[128 * 64];                                         \
  __shared__ unsigned short Bs[128 * 64];                                         \
  const int tid = threadIdx.x;                                                    \
  const int lane = tid & 63;                                                      \
  const int wave = tid >> 6;                                                      \
  const int wm = wave & 1;                                                        \
  const int wn = wave >> 1;                                                       \
  const int m_base = blockIdx.x * 128;                                            \
  const int n_base = blockIdx.y * 128;                                            \
  const int lane31 = lane & 31;                                                   \
  const int khalf = lane >> 5;                                                    \
  const int l7 = lane & 7;                                                        \
  const int srow = lane >> 3;                                                     \
  const int sk = ((lane & 7) ^ srow) * 8;                                         \
  const unsigned short* gA0 = A_ + (size_t)(m_base + wave * 8 + srow) * 512 + sk; \
  const unsigned short* gA1 = gA0 + 32 * 512;                                     \
  const unsigned short* gA2 = gA0 + 64 * 512;                                     \
  const unsigned short* gA3 = gA0 + 96 * 512;                                     \
  const unsigned short* gB0 = Bt_ + (size_t)(n_base + wave * 8 + srow) * 512 + sk;\
  const unsigned short* gB1 = gB0 + 32 * 512;                                     \
  const unsigned short* gB2 = gB0 + 64 * 512;                                     \
  const unsigned short* gB3 = gB0 + 96 * 512;                                     \
  unsigned short* lA0 = As + wave * 512;                                          \
  unsigned short* lA1 = As + (4 + wave) * 512;                                    \
  unsigned short* lA2 = As + (8 + wave) * 512;                                    \
  unsigned short* lA3 = As + (12 + wave) * 512;                                   \
  unsigned short* lB0 = Bs + wave * 512;                                          \
  unsigned short* lB1 = Bs + (4 + wave) * 512;                                    \
  unsigned short* lB2 = Bs + (8 + wave) * 512;                                    \
  unsigned short* lB3 = Bs + (12 + wave) * 512;                                   \
  f32x16 acc[2][2];                                                               \
  _Pragma("unroll") for (int i = 0; i < 2; ++i)                                   \
      _Pragma("unroll") for (int j = 0; j < 2; ++j)                               \
          _Pragma("unroll") for (int r = 0; r < 16; ++r) acc[i][j][r] = 0.f;      \
  const int arow0 = (wm * 64 + lane31) * 64;                                      \
  const int arow1 = (wm * 64 + 32 + lane31) * 64;                                 \
  const int brow0 = (wn * 64 + lane31) * 64;                                      \
  const int brow1 = (wn * 64 + 32 + lane31) * 64;                                 \
  for (int k0 = 0; k0 < 512; k0 += 64) {                                          \
    gload16(gA0, lA0); gload16(gA1, lA1); gload16(gA2, lA2); gload16(gA3, lA3);   \
    gload16(gB0, lB0); gload16(gB1, lB1); gload16(gB2, lB2); gload16(gB3, lB3);   \
    gA0 += 64; gA1 += 64; gA2 += 64; gA3 += 64;                                   \
    gB0 += 64; gB1 += 64; gB2 += 64; gB3 += 64;                                   \
    __syncthreads();                                                              \
    _Pragma("unroll") for (int kc = 0; kc < 4; ++kc) {                            \
      const int ko = ((kc * 2 + khalf) ^ l7) * 8;                                 \
      short8 a0 = *(const short8*)(&As[arow0 + ko]);                              \
      short8 a1 = *(const short8*)(&As[arow1 + ko]);                              \
      short8 b0 = *(const short8*)(&Bs[brow0 + ko]);                              \
      short8 b1v = *(const short8*)(&Bs[brow1 + ko]);                             \
      acc[0][0] = __builtin_amdgcn_mfma_f32_32x32x16_bf16(a0, b0, acc[0][0], 0, 0, 0); \
      acc[0][1] = __builtin_amdgcn_mfma_f32_32x32x16_bf16(a0, b1v, acc[0][1], 0, 0, 0); \
      acc[1][0] = __builtin_amdgcn_mfma_f32_32x32x16_bf16(a1, b0, acc[1][0], 0, 0, 0); \
      acc[1][1] = __builtin_amdgcn_mfma_f32_32x32x16_bf16(a1, b1v, acc[1][1], 0, 0, 0); \
    }                                                                             \
    __syncthreads();                                                              \
  }

// row within 32x32 C/D frag for register r: (r&3) + 8*(r>>2) + 4*khalf
#define CD_ROW(r) (((r) & 3) + 8 * ((r) >> 2))

// ---- phase 1: x @ [qW1 | cW1] -> relu.w2m row reduction -> rowadd ----------
__global__ __launch_bounds__(256) void nl_gemm(
    const unsigned short* __restrict__ A,    // 16384 x 512 bf16
    const unsigned short* __restrict__ Bt,   // 1024 x 512 bf16 (WT rows 512..1535)
    const float* __restrict__ qb1, const float* __restrict__ cb1,
    const float* __restrict__ qw2m, const float* __restrict__ cw2m,
    float* __restrict__ rowadd) {
  GEMM_MAINLOOP(A, Bt)
  const int rbase = m_base + wm * 64 + 4 * khalf;  // + i*32 + CD_ROW(r)
  const bool isq = (blockIdx.y < 4);
  const float* b1 = isq ? qb1 : cb1;
  const float* w2m = isq ? qw2m : cw2m;
  const int cb0 = (isq ? n_base : n_base - 512) + wn * 64 + lane31;
  float rs[2][16];
#pragma unroll
  for (int i = 0; i < 2; ++i)
#pragma unroll
    for (int r = 0; r < 16; ++r) rs[i][r] = 0.f;
#pragma unroll
  for (int j = 0; j < 2; ++j) {
    int col = cb0 + j * 32;
    float bb = b1[col];
    float ww = w2m[col];
#pragma unroll
    for (int i = 0; i < 2; ++i)
#pragma unroll
      for (int r = 0; r < 16; ++r)
        rs[i][r] += fmaxf(acc[i][j][r] + bb, 0.f) * ww;
  }
#pragma unroll
  for (int i = 0; i < 2; ++i)
#pragma unroll
    for (int r = 0; r < 16; ++r) {
      float v = rs[i][r];
      v += __shfl_xor(v, 1, 64);
      v += __shfl_xor(v, 2, 64);
      v += __shfl_xor(v, 4, 64);
      v += __shfl_xor(v, 8, 64);
      v += __shfl_xor(v, 16, 64);
      if (lane31 == 0) atomicAdd(&rowadd[rbase + i * 32 + CD_ROW(r)], v);
    }
}

// ---- phase 2: x @ L^T, epilogue folds rowadd + b2 means + enso -> out ------
__global__ __launch_bounds__(256) void lin_gemm(
    const unsigned short* __restrict__ A,    // 16384 x 512 bf16
    const unsigned short* __restrict__ Bt,   // 512 x 512 bf16 (WT rows 0..511)
    const float* __restrict__ rowadd, const float* __restrict__ b2m,
    const float* __restrict__ cT, const float* __restrict__ cH,
    float* __restrict__ out) {
  GEMM_MAINLOOP(A, Bt)
  const int rbase = m_base + wm * 64 + 4 * khalf;
  const float b2s = b2m[0] + b2m[1];
  float ra[2][16];
#pragma unroll
  for (int i = 0; i < 2; ++i)
#pragma unroll
    for (int r = 0; r < 16; ++r)
      ra[i][r] = rowadd[rbase + i * 32 + CD_ROW(r)] + b2s;
#pragma unroll
  for (int j = 0; j < 2; ++j) {
    int col = n_base + wn * 64 + j * 32 + lane31;
#pragma unroll
    for (int i = 0; i < 2; ++i)
#pragma unroll
      for (int r = 0; r < 16; ++r) {
        int row = rbase + i * 32 + CD_ROW(r);
        float v = acc[i][j][r] + ra[i][r];
        if (col == 0) v += cT[row];
        if (col == 1) v += cH[row];
        out[(size_t)row * 512 + col] = v;
      }
  }
}

extern "C" void kernel_launch(void* const* d_in, const int* in_sizes, int n_in,
                              void* d_out, int out_size, void* d_ws, size_t ws_size,
                              hipStream_t stream) {
  const float* x   = (const float*)d_in[0];
  const float* t   = (const float*)d_in[1];
  const float* fc  = (const float*)d_in[2];
  const float* qW1 = (const float*)d_in[3];
  const float* qb1 = (const float*)d_in[4];
  const float* qW2 = (const float*)d_in[5];
  const float* qb2 = (const float*)d_in[6];
  const float* cW1 = (const float*)d_in[7];
  const float* cb1 = (const float*)d_in[8];
  const float* cW2 = (const float*)d_in[9];
  const float* cb2 = (const float*)d_in[10];
  const float* tW1 = (const float*)d_in[11];
  const float* tb1 = (const float*)d_in[12];
  const float* tW2 = (const float*)d_in[13];
  const float* tb2 = (const float*)d_in[14];
  const float* hW1 = (const float*)d_in[15];
  const float* hb1 = (const float*)d_in[16];
  const float* hW2 = (const float*)d_in[17];
  const float* hb2 = (const float*)d_in[18];
  float* out = (float*)d_out;

  // workspace layout (bytes); total ~18.6 MB
  char* ws = (char*)d_ws;
  unsigned short* WT = (unsigned short*)(ws);              // 1536*512*2   = 1,572,864
  unsigned short* xb = (unsigned short*)(ws + 1572864);    // 16384*512*2  = 16,777,216
  float* qw2m   = (float*)(ws + 18350080);                 // 512*4
  float* cw2m   = (float*)(ws + 18352128);                 // 512*4
  float* b2m    = (float*)(ws + 18354176);                 // 2*4 (pad)
  float* cT     = (float*)(ws + 18354432);                 // 16384*4
  float* cH     = (float*)(ws + 18419968);                 // 16384*4
  float* rowadd = (float*)(ws + 18485504);                 // 16384*4 -> ends 18,551,040

  prep_conv<<<11333, 256, 0, stream>>>(fc, qW1, cW1, t, qW2, cW2, qb2, cb2,
                                       (const float4*)x, x,
                                       tW1, tb1, tW2, tb2, hW1, hb1, hW2, hb2,
                                       WT, (uint2*)xb, qw2m, cw2m, b2m, cT, cH,
                                       rowadd);
  nl_gemm<<<dim3(128, 8), 256, 0, stream>>>(xb, WT + (size_t)512 * 512,
                                            qb1, cb1, qw2m, cw2m, rowadd);
  lin_gemm<<<dim3(128, 4), 256, 0, stream>>>(xb, WT, rowadd, b2m, cT, cH, out);
}

// Round 7
// 172.854 us; speedup vs baseline: 1.1096x; 1.1096x over previous
//
#include <hip/hip_runtime.h>

// ---------------------------------------------------------------------------
// out[b,i] = (x@L^T)[b,i] + quad_mean[b] + cubic_mean[b] + (i==0)*cT[b] + (i==1)*cH[b]
// quad_mean[b] = sum_h relu(x@qW1 + qb1)[b,h] * colmean(qW2)[h] + mean(qb2)
//
// Round 7: REVERT to round-5 configuration (best measured: 176.9 us).
// Round 6's 32x32x16 MFMA switch regressed 15 us (4 accumulator chains expose
// MFMA latency; 16x16x32 with 16 chains interleaves better) — reverted.
// Config: BK=64, 128x128 tile, 16x16x32 bf16 MFMA, global_load_lds(16B)
// staging, XOR swizzle chunk(row,kc)->slot kc^(row&7) (conflict-free).
// Structure: prep_conv -> nl_gemm -> lin_gemm (3 launches).
// ---------------------------------------------------------------------------

#define OMEGA_F 0.5235987755982988f

typedef __attribute__((ext_vector_type(8))) short short8;
typedef __attribute__((ext_vector_type(4))) float f32x4;

__device__ __forceinline__ unsigned short f2bf(float f) {
  union { float f; unsigned int u; } a;
  a.f = f;
  unsigned int u = a.u;
  return (unsigned short)((u + 0x7fffu + ((u >> 16) & 1u)) >> 16);
}

// async global -> LDS, 16 B per lane; LDS dst wave-uniform, lane i -> base+i*16
__device__ __forceinline__ void gload16(const void* g, void* l) {
  __builtin_amdgcn_global_load_lds(
      (const __attribute__((address_space(1))) unsigned int*)g,
      (__attribute__((address_space(3))) unsigned int*)l, 16, 0, 0);
}

// ---- k1: all prep work in one launch ---------------------------------------
__global__ void prep_conv(const float* __restrict__ fc, const float* __restrict__ qW1,
                          const float* __restrict__ cW1, const float* __restrict__ t,
                          const float* __restrict__ qW2, const float* __restrict__ cW2,
                          const float* __restrict__ qb2, const float* __restrict__ cb2,
                          const float4* __restrict__ x4, const float* __restrict__ x,
                          const float* __restrict__ tW1, const float* __restrict__ tb1,
                          const float* __restrict__ tW2, const float* __restrict__ tb2,
                          const float* __restrict__ hW1, const float* __restrict__ hb1,
                          const float* __restrict__ hW2, const float* __restrict__ hb2,
                          unsigned short* __restrict__ WT, uint2* __restrict__ xb,
                          float* __restrict__ qw2m, float* __restrict__ cw2m,
                          float* __restrict__ b2m, float* __restrict__ cT,
                          float* __restrict__ cH, float* __restrict__ rowadd) {
  int b = blockIdx.x, tdx = threadIdx.x;
  if (b < 3072) {
    // WcatT (1536 x 512 bf16, n-major): [ L | quad_W1^T | cubic_W1^T ]
    int idx = b * 256 + tdx;
    int n = idx >> 9;
    int k = idx & 511;
    float v;
    if (n < 512) {
      float th = OMEGA_F * t[0];
      float s1, c1, s2, c2;
      sincosf(th, &s1, &c1);
      sincosf(2.0f * th, &s2, &c2);
      const float* p = fc + ((size_t)n * 512 + k) * 5;
      v = p[0] + p[1] * c1 + p[2] * s1 + p[3] * c2 + p[4] * s2;
    } else if (n < 1024) {
      v = qW1[(size_t)k * 512 + (n - 512)];
    } else {
      v = cW1[(size_t)k * 512 + (n - 1024)];
    }
    WT[idx] = f2bf(v);
  } else if (b < 3076) {
    int bb = b - 3072;
    const float* W = (bb < 2) ? qW2 : cW2;
    float* o = (bb < 2) ? qw2m : cw2m;
    int h = (bb & 1) * 256 + tdx;
    const float4* row = (const float4*)(W + (size_t)h * 512);
    float s = 0.f;
    for (int i = 0; i < 128; ++i) { float4 v = row[i]; s += (v.x + v.y) + (v.z + v.w); }
    o[h] = s * (1.0f / 512.0f);
  } else if (b == 3076) {
    __shared__ float sm[256];
    sm[tdx] = qb2[tdx] + qb2[tdx + 256];
    __syncthreads();
    for (int w = 128; w > 0; w >>= 1) { if (tdx < w) sm[tdx] += sm[tdx + w]; __syncthreads(); }
    if (tdx == 0) b2m[0] = sm[0] * (1.0f / 512.0f);
    __syncthreads();
    sm[tdx] = cb2[tdx] + cb2[tdx + 256];
    __syncthreads();
    for (int w = 128; w > 0; w >>= 1) { if (tdx < w) sm[tdx] += sm[tdx + w]; __syncthreads(); }
    if (tdx == 0) b2m[1] = sm[0] * (1.0f / 512.0f);
  } else if (b < 3077 + 8192) {
    // x -> bf16
    int i = (b - 3077) * 256 + tdx;
    float4 v = x4[i];
    uint2 r;
    r.x = (unsigned)f2bf(v.x) | ((unsigned)f2bf(v.y) << 16);
    r.y = (unsigned)f2bf(v.z) | ((unsigned)f2bf(v.w) << 16);
    xb[i] = r;
  } else {
    // enso tiny MLPs + rowadd zeroing
    int row = (b - 11269) * 256 + tdx;
    rowadd[row] = 0.f;
    float T = x[(size_t)row * 512];
    float H = x[(size_t)row * 512 + 1];
    float fT[5] = {T, H, T * T, T * H, T * T * T};
    float fH[5] = {T, H, T * T, T * H, T * H * H};
    float sT = tb2[0], sH = hb2[0];
#pragma unroll 4
    for (int e = 0; e < 32; ++e) {
      float a1 = tb1[e], a2 = hb1[e];
#pragma unroll
      for (int f = 0; f < 5; ++f) {
        a1 += fT[f] * tW1[f * 32 + e];
        a2 += fH[f] * hW1[f * 32 + e];
      }
      sT += fmaxf(a1, 0.f) * tW2[e];
      sH += fmaxf(a2, 0.f) * hW2[e];
    }
    cT[row] = sT;
    cH[row] = sH;
  }
}

// ---------------------------------------------------------------------------
// GEMM main loop: 128x128 tile, BK=64, global_load_lds(16B) staging.
// LDS layout: row-major 128 x 64 elems (128 B/row = exact bank wrap), 16B
// chunk (row, kc) stored at slot kc ^ (row&7).
//  - staging: issue i, wave w covers rows (i*4+w)*8 .. +7; lane l -> row
//    +(l>>3), slot l&7, so it must fetch global chunk (l&7)^(l>>3): the 8
//    lanes of a row permute chunks within one 128 B segment (coalesced).
//  - read: frag k-chunk kc = h*4 + (lane>>4) at slot kc ^ (lrow&7); bank-quad
//    = slot -> each 8-lane octet covers all 8 quads: conflict-free.
// ---------------------------------------------------------------------------
#define GEMM_MAINLOOP(A_, Bt_)                                                    \
  __shared__ unsigned short As[128 * 64];                                         \
  __shared__ unsigned short Bs[128 * 64];                                         \
  const int tid = threadIdx.x;                                                    \
  const int lane = tid & 63;                                                      \
  const int wave = tid >> 6;                                                      \
  const int wm = wave & 1;                                                        \
  const int wn = wave >> 1;                                                       \
  const int m_base = blockIdx.x * 128;                                            \
  const int n_base = blockIdx.y * 128;                                            \
  const int lrow = lane & 15;                                                     \
  const int l7 = lrow & 7;                                                        \
  const int kgrp = lane >> 4;                                                     \
  const int srow = lane >> 3;                                                     \
  const int sk = ((lane & 7) ^ srow) * 8;                                         \
  const unsigned short* gA0 = A_ + (size_t)(m_base + wave * 8 + srow) * 512 + sk; \
  const unsigned short* gA1 = gA0 + 32 * 512;                                     \
  const unsigned short* gA2 = gA0 + 64 * 512;                                     \
  const unsigned short* gA3 = gA0 + 96 * 512;                                     \
  const unsigned short* gB0 = Bt_ + (size_t)(n_base + wave * 8 + srow) * 512 + sk;\
  const unsigned short* gB1 = gB0 + 32 * 512;                                     \
  const unsigned short* gB2 = gB0 + 64 * 512;                                     \
  const unsigned short* gB3 = gB0 + 96 * 512;                                     \
  unsigned short* lA0 = As + wave * 512;                                          \
  unsigned short* lA1 = As + (4 + wave) * 512;                                    \
  unsigned short* lA2 = As + (8 + wave) * 512;                                    \
  unsigned short* lA3 = As + (12 + wave) * 512;                                   \
  unsigned short* lB0 = Bs + wave * 512;                                          \
  unsigned short* lB1 = Bs + (4 + wave) * 512;                                    \
  unsigned short* lB2 = Bs + (8 + wave) * 512;                                    \
  unsigned short* lB3 = Bs + (12 + wave) * 512;                                   \
  f32x4 acc[4][4];                                                                \
  _Pragma("unroll") for (int i = 0; i < 4; ++i)                                   \
      _Pragma("unroll") for (int j = 0; j < 4; ++j)                               \
          acc[i][j] = (f32x4){0.f, 0.f, 0.f, 0.f};                                \
  for (int k0 = 0; k0 < 512; k0 += 64) {                                          \
    gload16(gA0, lA0); gload16(gA1, lA1); gload16(gA2, lA2); gload16(gA3, lA3);   \
    gload16(gB0, lB0); gload16(gB1, lB1); gload16(gB2, lB2); gload16(gB3, lB3);   \
    gA0 += 64; gA1 += 64; gA2 += 64; gA3 += 64;                                   \
    gB0 += 64; gB1 += 64; gB2 += 64; gB3 += 64;                                   \
    __syncthreads();                                                              \
    _Pragma("unroll") for (int h = 0; h < 2; ++h) {                               \
      short8 af[4], bfr[4];                                                       \
      const int ks = ((h * 4 + kgrp) ^ l7) * 8;                                   \
      _Pragma("unroll") for (int i = 0; i < 4; ++i)                               \
          af[i] = *(const short8*)(&As[(wm * 64 + i * 16 + lrow) * 64 + ks]);     \
      _Pragma("unroll") for (int j = 0; j < 4; ++j)                               \
          bfr[j] = *(const short8*)(&Bs[(wn * 64 + j * 16 + lrow) * 64 + ks]);    \
      _Pragma("unroll") for (int i = 0; i < 4; ++i)                               \
          _Pragma("unroll") for (int j = 0; j < 4; ++j)                           \
              acc[i][j] = __builtin_amdgcn_mfma_f32_16x16x32_bf16(af[i], bfr[j],  \
                                                                  acc[i][j], 0, 0, 0); \
    }                                                                             \
    __syncthreads();                                                              \
  }

// ---- phase 1: x @ [qW1 | cW1] -> relu.w2m row reduction -> rowadd ----------
__global__ __launch_bounds__(256) void nl_gemm(
    const unsigned short* __restrict__ A,    // 16384 x 512 bf16
    const unsigned short* __restrict__ Bt,   // 1024 x 512 bf16 (WT rows 512..1535)
    const float* __restrict__ qb1, const float* __restrict__ cb1,
    const float* __restrict__ qw2m, const float* __restrict__ cw2m,
    float* __restrict__ rowadd) {
  GEMM_MAINLOOP(A, Bt)
  // C/D: col = lane&15, row = (lane>>4)*4 + reg (m89/m91)
  const int rbase = m_base + wm * 64 + (lane >> 4) * 4;
  const bool isq = (blockIdx.y < 4);
  const float* b1 = isq ? qb1 : cb1;
  const float* w2m = isq ? qw2m : cw2m;
  const int cb0 = (isq ? n_base : n_base - 512) + wn * 64 + lrow;
  float rs[4][4];
#pragma unroll
  for (int i = 0; i < 4; ++i)
#pragma unroll
    for (int r = 0; r < 4; ++r) rs[i][r] = 0.f;
#pragma unroll
  for (int j = 0; j < 4; ++j) {
    int col = cb0 + j * 16;
    float bb = b1[col];
    float ww = w2m[col];
#pragma unroll
    for (int i = 0; i < 4; ++i)
#pragma unroll
      for (int r = 0; r < 4; ++r)
        rs[i][r] += fmaxf(acc[i][j][r] + bb, 0.f) * ww;
  }
#pragma unroll
  for (int i = 0; i < 4; ++i)
#pragma unroll
    for (int r = 0; r < 4; ++r) {
      float v = rs[i][r];
      v += __shfl_xor(v, 1, 64);
      v += __shfl_xor(v, 2, 64);
      v += __shfl_xor(v, 4, 64);
      v += __shfl_xor(v, 8, 64);
      if (lrow == 0) atomicAdd(&rowadd[rbase + i * 16 + r], v);
    }
}

// ---- phase 2: x @ L^T, epilogue folds rowadd + b2 means + enso -> out ------
__global__ __launch_bounds__(256) void lin_gemm(
    const unsigned short* __restrict__ A,    // 16384 x 512 bf16
    const unsigned short* __restrict__ Bt,   // 512 x 512 bf16 (WT rows 0..511)
    const float* __restrict__ rowadd, const float* __restrict__ b2m,
    const float* __restrict__ cT, const float* __restrict__ cH,
    float* __restrict__ out) {
  GEMM_MAINLOOP(A, Bt)
  const int rbase = m_base + wm * 64 + (lane >> 4) * 4;
  const float b2s = b2m[0] + b2m[1];
  float ra[4][4];
#pragma unroll
  for (int i = 0; i < 4; ++i)
#pragma unroll
    for (int r = 0; r < 4; ++r) ra[i][r] = rowadd[rbase + i * 16 + r] + b2s;
#pragma unroll
  for (int j = 0; j < 4; ++j) {
    int col = n_base + wn * 64 + j * 16 + lrow;
#pragma unroll
    for (int i = 0; i < 4; ++i)
#pragma unroll
      for (int r = 0; r < 4; ++r) {
        int row = rbase + i * 16 + r;
        float v = acc[i][j][r] + ra[i][r];
        if (col == 0) v += cT[row];
        if (col == 1) v += cH[row];
        out[(size_t)row * 512 + col] = v;
      }
  }
}

extern "C" void kernel_launch(void* const* d_in, const int* in_sizes, int n_in,
                              void* d_out, int out_size, void* d_ws, size_t ws_size,
                              hipStream_t stream) {
  const float* x   = (const float*)d_in[0];
  const float* t   = (const float*)d_in[1];
  const float* fc  = (const float*)d_in[2];
  const float* qW1 = (const float*)d_in[3];
  const float* qb1 = (const float*)d_in[4];
  const float* qW2 = (const float*)d_in[5];
  const float* qb2 = (const float*)d_in[6];
  const float* cW1 = (const float*)d_in[7];
  const float* cb1 = (const float*)d_in[8];
  const float* cW2 = (const float*)d_in[9];
  const float* cb2 = (const float*)d_in[10];
  const float* tW1 = (const float*)d_in[11];
  const float* tb1 = (const float*)d_in[12];
  const float* tW2 = (const float*)d_in[13];
  const float* tb2 = (const float*)d_in[14];
  const float* hW1 = (const float*)d_in[15];
  const float* hb1 = (const float*)d_in[16];
  const float* hW2 = (const float*)d_in[17];
  const float* hb2 = (const float*)d_in[18];
  float* out = (float*)d_out;

  // workspace layout (bytes); total ~18.6 MB
  char* ws = (char*)d_ws;
  unsigned short* WT = (unsigned short*)(ws);              // 1536*512*2   = 1,572,864
  unsigned short* xb = (unsigned short*)(ws + 1572864);    // 16384*512*2  = 16,777,216
  float* qw2m   = (float*)(ws + 18350080);                 // 512*4
  float* cw2m   = (float*)(ws + 18352128);                 // 512*4
  float* b2m    = (float*)(ws + 18354176);                 // 2*4 (pad)
  float* cT     = (float*)(ws + 18354432);                 // 16384*4
  float* cH     = (float*)(ws + 18419968);                 // 16384*4
  float* rowadd = (float*)(ws + 18485504);                 // 16384*4 -> ends 18,551,040

  prep_conv<<<11333, 256, 0, stream>>>(fc, qW1, cW1, t, qW2, cW2, qb2, cb2,
                                       (const float4*)x, x,
                                       tW1, tb1, tW2, tb2, hW1, hb1, hW2, hb2,
                                       WT, (uint2*)xb, qw2m, cw2m, b2m, cT, cH,
                                       rowadd);
  nl_gemm<<<dim3(128, 8), 256, 0, stream>>>(xb, WT + (size_t)512 * 512,
                                            qb1, cb1, qw2m, cw2m, rowadd);
  lin_gemm<<<dim3(128, 4), 256, 0, stream>>>(xb, WT, rowadd, b2m, cT, cH, out);
}